// Round 1
// baseline (2865.752 us; speedup 1.0000x reference)
//
#include <hip/hip_runtime.h>

#define NNODES 50000
#define NREL 1000
#define NEDGES 1600000
#define FOUT 64
#define NEG_SLOPE 0.2f

// Edge pass: 16 lanes per edge, each lane owns 4 consecutive features.
// Computes both heads in one pass (head1 src = head0 src * w, elementwise).
// Accumulates messages directly into out[2][N][64] and edge_e sums into
// rowsum[2][N] via device-scope f32 atomics.
__global__ __launch_bounds__(256) void rgat_edge_kernel(
    const float* __restrict__ h,
    const float* __restrict__ inputr,
    const int* __restrict__ A,
    const float* __restrict__ w,
    const float* __restrict__ a_att,   // [2,2,64]
    float* __restrict__ out,           // [2,N,64] accumulator
    float* __restrict__ rowsum)        // [2,N]
{
    const int tid     = blockIdx.x * blockDim.x + threadIdx.x;
    const int fq      = tid & 15;        // which float4 of the 64 features
    const int f0      = fq << 2;
    const int group   = tid >> 4;        // edge-group id
    const int ngroups = (gridDim.x * blockDim.x) >> 4;

    // Per-lane attention params (fixed per lane across the grid-stride loop).
    const float4 a00 = *(const float4*)(a_att +   0 + f0);  // head0, src
    const float4 a01 = *(const float4*)(a_att +  64 + f0);  // head0, rel
    const float4 a10 = *(const float4*)(a_att + 128 + f0);  // head1, src
    const float4 a11 = *(const float4*)(a_att + 192 + f0);  // head1, rel
    const float4 wv  = *(const float4*)(w + f0);

    const int* __restrict__ dstA = A;
    const int* __restrict__ relA = A + NEDGES;
    const int* __restrict__ srcA = A + 2 * NEDGES;

    for (int e = group; e < NEDGES; e += ngroups) {
        const int dn = dstA[e];
        const int rn = relA[e];
        const int sn = srcA[e];

        const float4 s = *(const float4*)(h      + (size_t)sn * FOUT + f0);
        const float4 r = *(const float4*)(inputr + (size_t)rn * FOUT + f0);
        const float4 s1 = make_float4(s.x * wv.x, s.y * wv.y, s.z * wv.z, s.w * wv.w);

        // Per-lane partial dot products for both heads.
        float p0 = s.x * a00.x + s.y * a00.y + s.z * a00.z + s.w * a00.w
                 + r.x * a01.x + r.y * a01.y + r.z * a01.z + r.w * a01.w;
        float p1 = s1.x * a10.x + s1.y * a10.y + s1.z * a10.z + s1.w * a10.w
                 + r.x  * a11.x + r.y  * a11.y + r.z  * a11.z + r.w  * a11.w;

        // Reduce across the 16 lanes of this edge-group.
        #pragma unroll
        for (int off = 8; off >= 1; off >>= 1) {
            p0 += __shfl_xor(p0, off, 16);
            p1 += __shfl_xor(p1, off, 16);
        }

        const float l0 = p0 > 0.f ? p0 : NEG_SLOPE * p0;
        const float l1 = p1 > 0.f ? p1 : NEG_SLOPE * p1;
        const float e0 = __expf(-l0);
        const float e1 = __expf(-l1);

        float* o0 = out + (size_t)dn * FOUT + f0;                 // head 0
        float* o1 = out + ((size_t)NNODES + dn) * FOUT + f0;      // head 1

        atomicAdd(o0 + 0, (s.x - r.x) * e0);
        atomicAdd(o0 + 1, (s.y - r.y) * e0);
        atomicAdd(o0 + 2, (s.z - r.z) * e0);
        atomicAdd(o0 + 3, (s.w - r.w) * e0);
        atomicAdd(o1 + 0, (s1.x - r.x) * e1);
        atomicAdd(o1 + 1, (s1.y - r.y) * e1);
        atomicAdd(o1 + 2, (s1.z - r.z) * e1);
        atomicAdd(o1 + 3, (s1.w - r.w) * e1);

        if (fq == 0) {
            atomicAdd(rowsum + dn, e0);
            atomicAdd(rowsum + NNODES + dn, e1);
        }
    }
}

// out[row][f] /= rowsum[row], row in [0, 2N), vectorized float4.
__global__ __launch_bounds__(256) void rgat_norm_kernel(
    float* __restrict__ out, const float* __restrict__ rowsum)
{
    const int i = blockIdx.x * blockDim.x + threadIdx.x;
    const int total = 2 * NNODES * (FOUT / 4);
    if (i < total) {
        const int row = i >> 4;   // 16 float4s per 64-feature row
        const float inv = 1.0f / rowsum[row];
        float4* p = reinterpret_cast<float4*>(out) + i;
        float4 v = *p;
        v.x *= inv; v.y *= inv; v.z *= inv; v.w *= inv;
        *p = v;
    }
}

extern "C" void kernel_launch(void* const* d_in, const int* in_sizes, int n_in,
                              void* d_out, int out_size, void* d_ws, size_t ws_size,
                              hipStream_t stream) {
    const float* h      = (const float*)d_in[0];
    const float* inputr = (const float*)d_in[1];
    const int*   A      = (const int*)d_in[2];
    const float* w      = (const float*)d_in[3];
    const float* a_att  = (const float*)d_in[4];

    float* out    = (float*)d_out;
    float* rowsum = (float*)d_ws;   // 2*N floats = 400 KB

    // Zero accumulators (graph-capture-safe memset nodes).
    hipMemsetAsync(d_out, 0, (size_t)out_size * sizeof(float), stream);
    hipMemsetAsync(rowsum, 0, (size_t)(2 * NNODES) * sizeof(float), stream);

    // Edge pass: 2048 blocks x 256 threads = 32768 edge-groups, grid-stride.
    rgat_edge_kernel<<<dim3(2048), dim3(256), 0, stream>>>(
        h, inputr, A, w, a_att, out, rowsum);

    // Normalize.
    const int total4 = 2 * NNODES * (FOUT / 4);
    rgat_norm_kernel<<<dim3((total4 + 255) / 256), dim3(256), 0, stream>>>(out, rowsum);
}

// Round 2
// 484.656 us; speedup vs baseline: 5.9130x; 5.9130x over previous
//
#include <hip/hip_runtime.h>

#define NNODES 50000
#define NREL   1000
#define NEDGES 1600000
#define FOUT   64
#define NEG_SLOPE 0.2f

// -------- ws layout (bytes, 1 KiB aligned) --------
// counts : int  [NNODES]
// start  : int  [NNODES+1]
// next   : int  [NNODES]
// hs2    : float2[NNODES]   (per-node src-score, head0/head1)
// rr2    : float2[NREL]     (per-rel score, head0/head1)
// perm   : int  [NEDGES]    (packed sn<<10 | rn, CSR-sorted by dst)
#define ALIGN1K(x) (((x) + 1023) & ~((size_t)1023))
static const size_t OFF_COUNTS = 0;
static const size_t OFF_START  = ALIGN1K(OFF_COUNTS + sizeof(int) * NNODES);
static const size_t OFF_NEXT   = ALIGN1K(OFF_START  + sizeof(int) * (NNODES + 1));
static const size_t OFF_HS     = ALIGN1K(OFF_NEXT   + sizeof(int) * NNODES);
static const size_t OFF_RR     = ALIGN1K(OFF_HS     + sizeof(float2) * NNODES);
static const size_t OFF_PERM   = ALIGN1K(OFF_RR     + sizeof(float2) * NREL);

// Precompute per-node and per-rel attention scores (separable dot products).
// 16 lanes per row, each lane owns a float4 of the 64 features.
__global__ __launch_bounds__(256) void precompute_scores(
    const float* __restrict__ h, const float* __restrict__ inputr,
    const float* __restrict__ w, const float* __restrict__ a_att,
    float2* __restrict__ hs2, float2* __restrict__ rr2)
{
    const int tid  = blockIdx.x * blockDim.x + threadIdx.x;
    const int lane = tid & 15;
    const int f0   = lane << 2;
    const int g    = tid >> 4;
    if (g >= NNODES + NREL) return;

    const float4 a00 = *(const float4*)(a_att +   0 + f0);  // head0 src
    const float4 a01 = *(const float4*)(a_att +  64 + f0);  // head0 rel
    const float4 a10 = *(const float4*)(a_att + 128 + f0);  // head1 src
    const float4 a11 = *(const float4*)(a_att + 192 + f0);  // head1 rel
    const float4 wv  = *(const float4*)(w + f0);

    float p0, p1;
    if (g < NNODES) {
        const float4 v = *(const float4*)(h + (size_t)g * FOUT + f0);
        p0 = v.x * a00.x + v.y * a00.y + v.z * a00.z + v.w * a00.w;
        p1 = v.x * wv.x * a10.x + v.y * wv.y * a10.y
           + v.z * wv.z * a10.z + v.w * wv.w * a10.w;
    } else {
        const float4 v = *(const float4*)(inputr + (size_t)(g - NNODES) * FOUT + f0);
        p0 = v.x * a01.x + v.y * a01.y + v.z * a01.z + v.w * a01.w;
        p1 = v.x * a11.x + v.y * a11.y + v.z * a11.z + v.w * a11.w;
    }
    #pragma unroll
    for (int off = 8; off >= 1; off >>= 1) {
        p0 += __shfl_xor(p0, off, 16);
        p1 += __shfl_xor(p1, off, 16);
    }
    if (lane == 0) {
        if (g < NNODES) hs2[g] = make_float2(p0, p1);
        else            rr2[g - NNODES] = make_float2(p0, p1);
    }
}

__global__ __launch_bounds__(256) void count_kernel(
    const int* __restrict__ A, int* __restrict__ counts)
{
    const int e = blockIdx.x * blockDim.x + threadIdx.x;
    if (e < NEDGES) atomicAdd(&counts[A[e]], 1);
}

// Single-block exclusive scan over 50000 counts -> start[], next[] copies.
__global__ __launch_bounds__(1024) void scan_kernel(
    const int* __restrict__ counts, int* __restrict__ start, int* __restrict__ next)
{
    __shared__ int partial[1024];
    const int CH = 49;  // 1024*49 = 50176 >= 50000
    const int t = threadIdx.x;
    const int base = t * CH;
    int s = 0;
    for (int i = 0; i < CH; i++) {
        const int idx = base + i;
        if (idx < NNODES) s += counts[idx];
    }
    partial[t] = s;
    __syncthreads();
    for (int off = 1; off < 1024; off <<= 1) {
        const int v = (t >= off) ? partial[t - off] : 0;
        __syncthreads();
        partial[t] += v;
        __syncthreads();
    }
    int pre = (t == 0) ? 0 : partial[t - 1];
    for (int i = 0; i < CH; i++) {
        const int idx = base + i;
        if (idx < NNODES) {
            start[idx] = pre;
            next[idx]  = pre;
            pre += counts[idx];
        }
    }
    if (t == 1023) start[NNODES] = pre;
}

// Scatter packed (sn<<10 | rn) into CSR position by dst.
__global__ __launch_bounds__(256) void scatter_kernel(
    const int* __restrict__ A, int* __restrict__ next, int* __restrict__ perm)
{
    const int e = blockIdx.x * blockDim.x + threadIdx.x;
    if (e >= NEDGES) return;
    const int dn = A[e];
    const int rn = A[e + NEDGES];
    const int sn = A[e + 2 * NEDGES];
    const int pos = atomicAdd(&next[dn], 1);
    perm[pos] = (sn << 10) | rn;
}

// One 64-lane wave per dst node; lane = feature. Register accumulation,
// recompute edge_e from the score tables (broadcast loads), single write.
__global__ __launch_bounds__(256) void aggregate_kernel(
    const float* __restrict__ h, const float* __restrict__ inputr,
    const float* __restrict__ w,
    const int* __restrict__ perm, const int* __restrict__ start,
    const float2* __restrict__ hs2, const float2* __restrict__ rr2,
    float* __restrict__ out)
{
    const int wid  = (blockIdx.x * blockDim.x + threadIdx.x) >> 6;  // node id
    const int lane = threadIdx.x & 63;
    if (wid >= NNODES) return;

    const int b = start[wid];
    const int e = start[wid + 1];
    const float wl = w[lane];

    float acc0 = 0.f, acc1 = 0.f, sum0 = 0.f, sum1 = 0.f;
    for (int i = b; i < e; i++) {
        const int p  = perm[i];           // broadcast load
        const int sn = p >> 10;
        const int rn = p & 1023;
        const float2 hv = hs2[sn];        // broadcast 8B
        const float2 rv = rr2[rn];        // L1-resident
        const float sc0 = hv.x + rv.x;
        const float sc1 = hv.y + rv.y;
        const float e0 = __expf(-(sc0 > 0.f ? sc0 : NEG_SLOPE * sc0));
        const float e1 = __expf(-(sc1 > 0.f ? sc1 : NEG_SLOPE * sc1));
        const float s = h[(size_t)sn * FOUT + lane];
        const float r = inputr[(size_t)rn * FOUT + lane];
        acc0 += (s - r) * e0;
        acc1 += (s * wl - r) * e1;
        sum0 += e0;
        sum1 += e1;
    }
    out[(size_t)wid * FOUT + lane]            = acc0 / sum0;
    out[((size_t)NNODES + wid) * FOUT + lane] = acc1 / sum1;
}

extern "C" void kernel_launch(void* const* d_in, const int* in_sizes, int n_in,
                              void* d_out, int out_size, void* d_ws, size_t ws_size,
                              hipStream_t stream) {
    const float* h      = (const float*)d_in[0];
    const float* inputr = (const float*)d_in[1];
    const int*   A      = (const int*)d_in[2];
    const float* w      = (const float*)d_in[3];
    const float* a_att  = (const float*)d_in[4];

    char* ws = (char*)d_ws;
    int*    counts = (int*)(ws + OFF_COUNTS);
    int*    start  = (int*)(ws + OFF_START);
    int*    next   = (int*)(ws + OFF_NEXT);
    float2* hs2    = (float2*)(ws + OFF_HS);
    float2* rr2    = (float2*)(ws + OFF_RR);
    int*    perm   = (int*)(ws + OFF_PERM);
    float*  out    = (float*)d_out;

    hipMemsetAsync(counts, 0, sizeof(int) * NNODES, stream);

    // Per-node / per-rel separable score tables.
    {
        const int groups = NNODES + NREL;
        const int threads = groups * 16;
        precompute_scores<<<dim3((threads + 255) / 256), dim3(256), 0, stream>>>(
            h, inputr, w, a_att, hs2, rr2);
    }
    // Histogram by dst.
    count_kernel<<<dim3((NEDGES + 255) / 256), dim3(256), 0, stream>>>(A, counts);
    // Exclusive scan -> start / next.
    scan_kernel<<<dim3(1), dim3(1024), 0, stream>>>(counts, start, next);
    // Scatter packed edge records into CSR order.
    scatter_kernel<<<dim3((NEDGES + 255) / 256), dim3(256), 0, stream>>>(A, next, perm);
    // Aggregate: one wave per dst node, register accumulation, no f32 atomics.
    {
        const int waves = NNODES;
        const int threads = waves * 64;
        aggregate_kernel<<<dim3((threads + 255) / 256), dim3(256), 0, stream>>>(
            h, inputr, w, perm, start, hs2, rr2, out);
    }
}

// Round 3
// 311.672 us; speedup vs baseline: 9.1948x; 1.5550x over previous
//
#include <hip/hip_runtime.h>

#define NNODES 50000
#define NREL   1000
#define NEDGES 1600000
#define FOUT   64
#define NEG_SLOPE 0.2f
#define NBLK   196            // ceil(NNODES/256)
#define PAD_SENTINEL 0x80000000u

// -------- ws layout (bytes, 1 KiB aligned) --------
#define ALIGN1K(x) (((x) + 1023) & ~((size_t)1023))
static const size_t OFF_COUNTS = 0;
static const size_t OFF_START  = ALIGN1K(OFF_COUNTS + sizeof(int) * NNODES);
static const size_t OFF_NEXT   = ALIGN1K(OFF_START  + sizeof(int) * (NNODES + 1));
static const size_t OFF_SA     = ALIGN1K(OFF_NEXT   + sizeof(int) * NNODES);
static const size_t OFF_BSUM   = ALIGN1K(OFF_SA     + sizeof(int) * NNODES);
static const size_t OFF_BOFF   = ALIGN1K(OFF_BSUM   + sizeof(int) * 256);
static const size_t OFF_HS     = ALIGN1K(OFF_BOFF   + sizeof(int) * 256);
static const size_t OFF_RR     = ALIGN1K(OFF_HS     + sizeof(float2) * NNODES);
static const size_t OFF_PERM   = ALIGN1K(OFF_RR     + sizeof(float2) * NREL);
// perm: int[NEDGES + NNODES]  (CSR edges, padded to even per node)

// Separable score tables: hs2[n] = (h[n].a00, (h[n]*w).a10), rr2[r] likewise.
__global__ __launch_bounds__(256) void precompute_scores(
    const float* __restrict__ h, const float* __restrict__ inputr,
    const float* __restrict__ w, const float* __restrict__ a_att,
    float2* __restrict__ hs2, float2* __restrict__ rr2)
{
    const int tid  = blockIdx.x * blockDim.x + threadIdx.x;
    const int lane = tid & 15;
    const int f0   = lane << 2;
    const int g    = tid >> 4;
    if (g >= NNODES + NREL) return;

    const float4 a00 = *(const float4*)(a_att +   0 + f0);
    const float4 a01 = *(const float4*)(a_att +  64 + f0);
    const float4 a10 = *(const float4*)(a_att + 128 + f0);
    const float4 a11 = *(const float4*)(a_att + 192 + f0);
    const float4 wv  = *(const float4*)(w + f0);

    float p0, p1;
    if (g < NNODES) {
        const float4 v = *(const float4*)(h + (size_t)g * FOUT + f0);
        p0 = v.x * a00.x + v.y * a00.y + v.z * a00.z + v.w * a00.w;
        p1 = v.x * wv.x * a10.x + v.y * wv.y * a10.y
           + v.z * wv.z * a10.z + v.w * wv.w * a10.w;
    } else {
        const float4 v = *(const float4*)(inputr + (size_t)(g - NNODES) * FOUT + f0);
        p0 = v.x * a01.x + v.y * a01.y + v.z * a01.z + v.w * a01.w;
        p1 = v.x * a11.x + v.y * a11.y + v.z * a11.z + v.w * a11.w;
    }
    #pragma unroll
    for (int off = 8; off >= 1; off >>= 1) {
        p0 += __shfl_xor(p0, off, 16);
        p1 += __shfl_xor(p1, off, 16);
    }
    if (lane == 0) {
        if (g < NNODES) hs2[g] = make_float2(p0, p1);
        else            rr2[g - NNODES] = make_float2(p0, p1);
    }
}

__global__ __launch_bounds__(256) void count_kernel(
    const int* __restrict__ A, int* __restrict__ counts)
{
    const int e = blockIdx.x * blockDim.x + threadIdx.x;
    if (e < NEDGES) atomicAdd(&counts[A[e]], 1);
}

// Phase A: per-block exclusive scan of even-padded counts.
__global__ __launch_bounds__(256) void scanA_kernel(
    const int* __restrict__ counts, int* __restrict__ sA, int* __restrict__ bsum)
{
    __shared__ int sm[256];
    const int t = threadIdx.x;
    const int i = blockIdx.x * 256 + t;
    const int c  = (i < NNODES) ? counts[i] : 0;
    const int ce = c + (c & 1);                  // pad to even
    sm[t] = ce;
    __syncthreads();
    for (int off = 1; off < 256; off <<= 1) {
        const int v = (t >= off) ? sm[t - off] : 0;
        __syncthreads();
        sm[t] += v;
        __syncthreads();
    }
    if (i < NNODES) sA[i] = sm[t] - ce;          // exclusive
    if (t == 255) bsum[blockIdx.x] = sm[255];
}

// Phase B: scan the 196 block sums.
__global__ __launch_bounds__(256) void scanB_kernel(
    const int* __restrict__ bsum, int* __restrict__ boff)
{
    __shared__ int sm[256];
    const int t = threadIdx.x;
    const int v0 = (t < NBLK) ? bsum[t] : 0;
    sm[t] = v0;
    __syncthreads();
    for (int off = 1; off < 256; off <<= 1) {
        const int v = (t >= off) ? sm[t - off] : 0;
        __syncthreads();
        sm[t] += v;
        __syncthreads();
    }
    if (t < NBLK) boff[t] = sm[t] - v0;          // exclusive
}

// Phase C: final offsets; write start/next; pad odd-degree nodes with sentinel.
__global__ __launch_bounds__(256) void scanC_kernel(
    const int* __restrict__ counts, const int* __restrict__ sA,
    const int* __restrict__ boff,
    int* __restrict__ start, int* __restrict__ next, int* __restrict__ perm)
{
    const int i = blockIdx.x * 256 + threadIdx.x;
    if (i >= NNODES) return;
    const int s = sA[i] + boff[blockIdx.x];
    start[i] = s;
    next[i]  = s;
    const int c = counts[i];
    if (c & 1) perm[s + c] = (int)PAD_SENTINEL;  // pad slot
    if (i == NNODES - 1) start[NNODES] = s + c + (c & 1);
}

// Scatter packed (sn<<10 | rn) into CSR position by dst.
__global__ __launch_bounds__(256) void scatter_kernel(
    const int* __restrict__ A, int* __restrict__ next, int* __restrict__ perm)
{
    const int e = blockIdx.x * blockDim.x + threadIdx.x;
    if (e >= NEDGES) return;
    const int dn = A[e];
    const int rn = A[e + NEDGES];
    const int sn = A[e + 2 * NEDGES];
    const int pos = atomicAdd(&next[dn], 1);
    perm[pos] = (sn << 10) | rn;
}

// One wave per dst node; wave = 2 half-waves processing an edge PAIR per
// iteration; each lane owns a float2 feature pair. Pad sentinels contribute 0.
__global__ __launch_bounds__(256) void aggregate_kernel(
    const float* __restrict__ h, const float* __restrict__ inputr,
    const float* __restrict__ w,
    const int* __restrict__ perm, const int* __restrict__ start,
    const float2* __restrict__ hs2, const float2* __restrict__ rr2,
    float* __restrict__ out)
{
    const int wid  = (blockIdx.x * blockDim.x + threadIdx.x) >> 6;  // node id
    const int lane = threadIdx.x & 63;
    const int half = lane >> 5;        // which edge of the pair
    const int fp   = lane & 31;        // feature pair index (features 2fp, 2fp+1)
    if (wid >= NNODES) return;

    const int b  = start[wid];
    const int e2 = start[wid + 1];     // padded end (e2-b even)
    const float2 wl = *(const float2*)(w + 2 * fp);

    float2 acc0 = make_float2(0.f, 0.f);
    float2 acc1 = make_float2(0.f, 0.f);
    float sum0 = 0.f, sum1 = 0.f;

    for (int i = b + half; i < e2; i += 2) {
        const int p  = perm[i];                       // per-half broadcast
        const int sn = (p >> 10) & 0xFFFF;
        const int rn = p & 1023;

        const float2 hv = hs2[sn];
        const float2 rv = rr2[rn];
        const float sc0 = hv.x + rv.x;
        const float sc1 = hv.y + rv.y;
        // leaky_relu(x) = max(x, 0.2x); edge_e = exp(-that); pad -> 0
        float e0 = __expf(-fmaxf(sc0, NEG_SLOPE * sc0));
        float e1 = __expf(-fmaxf(sc1, NEG_SLOPE * sc1));
        if (p < 0) { e0 = 0.f; e1 = 0.f; }

        const float2 s = *(const float2*)(h      + (size_t)sn * FOUT + 2 * fp);
        const float2 r = *(const float2*)(inputr + (size_t)rn * FOUT + 2 * fp);

        acc0.x += (s.x - r.x) * e0;
        acc0.y += (s.y - r.y) * e0;
        acc1.x += fmaf(s.x, wl.x, -r.x) * e1;
        acc1.y += fmaf(s.y, wl.y, -r.y) * e1;
        sum0 += e0;
        sum1 += e1;
    }

    // Cross-half combine: xor-32 swap-add gives every lane the full totals.
    acc0.x += __shfl_xor(acc0.x, 32);
    acc0.y += __shfl_xor(acc0.y, 32);
    acc1.x += __shfl_xor(acc1.x, 32);
    acc1.y += __shfl_xor(acc1.y, 32);
    sum0   += __shfl_xor(sum0, 32);
    sum1   += __shfl_xor(sum1, 32);

    if (half == 0) {
        float2 o = make_float2(acc0.x / sum0, acc0.y / sum0);
        *(float2*)(out + (size_t)wid * FOUT + 2 * fp) = o;
    } else {
        float2 o = make_float2(acc1.x / sum1, acc1.y / sum1);
        *(float2*)(out + ((size_t)NNODES + wid) * FOUT + 2 * fp) = o;
    }
}

extern "C" void kernel_launch(void* const* d_in, const int* in_sizes, int n_in,
                              void* d_out, int out_size, void* d_ws, size_t ws_size,
                              hipStream_t stream) {
    const float* h      = (const float*)d_in[0];
    const float* inputr = (const float*)d_in[1];
    const int*   A      = (const int*)d_in[2];
    const float* w      = (const float*)d_in[3];
    const float* a_att  = (const float*)d_in[4];

    char* ws = (char*)d_ws;
    int*    counts = (int*)(ws + OFF_COUNTS);
    int*    start  = (int*)(ws + OFF_START);
    int*    next   = (int*)(ws + OFF_NEXT);
    int*    sA     = (int*)(ws + OFF_SA);
    int*    bsum   = (int*)(ws + OFF_BSUM);
    int*    boff   = (int*)(ws + OFF_BOFF);
    float2* hs2    = (float2*)(ws + OFF_HS);
    float2* rr2    = (float2*)(ws + OFF_RR);
    int*    perm   = (int*)(ws + OFF_PERM);
    float*  out    = (float*)d_out;

    hipMemsetAsync(counts, 0, sizeof(int) * NNODES, stream);

    {   // score tables
        const int groups = NNODES + NREL;
        precompute_scores<<<dim3((groups * 16 + 255) / 256), dim3(256), 0, stream>>>(
            h, inputr, w, a_att, hs2, rr2);
    }
    count_kernel<<<dim3((NEDGES + 255) / 256), dim3(256), 0, stream>>>(A, counts);
    scanA_kernel<<<dim3(NBLK), dim3(256), 0, stream>>>(counts, sA, bsum);
    scanB_kernel<<<dim3(1), dim3(256), 0, stream>>>(bsum, boff);
    scanC_kernel<<<dim3(NBLK), dim3(256), 0, stream>>>(counts, sA, boff, start, next, perm);
    scatter_kernel<<<dim3((NEDGES + 255) / 256), dim3(256), 0, stream>>>(A, next, perm);
    aggregate_kernel<<<dim3((NNODES * 64) / 256), dim3(256), 0, stream>>>(
        h, inputr, w, perm, start, hs2, rr2, out);
}

// Round 4
// 278.798 us; speedup vs baseline: 10.2789x; 1.1179x over previous
//
#include <hip/hip_runtime.h>

#define NNODES 50000
#define NREL   1000
#define NEDGES 1600000
#define FOUT   64
#define NEG_SLOPE 0.2f
#define NBLK   196            // ceil(NNODES/256)
#define CNT_BLOCKS 6250       // ceil(NEDGES/256)
#define PRE_BLOCKS 3188       // ceil((NNODES+NREL)/16)
#define PAD_SENTINEL 0x80000000u

// -------- ws layout (bytes, 1 KiB aligned) --------
#define ALIGN1K(x) (((x) + 1023) & ~((size_t)1023))
static const size_t OFF_COUNTS = 0;
static const size_t OFF_START  = ALIGN1K(OFF_COUNTS + sizeof(int) * NNODES);
static const size_t OFF_NEXT   = ALIGN1K(OFF_START  + sizeof(int) * (NNODES + 1));
static const size_t OFF_SA     = ALIGN1K(OFF_NEXT   + sizeof(int) * NNODES);
static const size_t OFF_BSUM   = ALIGN1K(OFF_SA     + sizeof(int) * NNODES);
static const size_t OFF_HS     = ALIGN1K(OFF_BSUM   + sizeof(int) * 256);
static const size_t OFF_RR     = ALIGN1K(OFF_HS     + sizeof(float2) * NNODES);
static const size_t OFF_PERM   = ALIGN1K(OFF_RR     + sizeof(float2) * NREL);
// perm: int[NEDGES + 3*NNODES]  (CSR edges, padded to multiple of 4 per node)

// Fused: blocks [0, CNT_BLOCKS) histogram dst; blocks [CNT_BLOCKS, ...) compute
// separable score tables hs2[n]=(h[n].a00,(h[n]*w).a10), rr2[r]=(r.a01,r.a11).
__global__ __launch_bounds__(256) void prep_kernel(
    const float* __restrict__ h, const float* __restrict__ inputr,
    const float* __restrict__ w, const float* __restrict__ a_att,
    const int* __restrict__ A, int* __restrict__ counts,
    float2* __restrict__ hs2, float2* __restrict__ rr2)
{
    if (blockIdx.x < CNT_BLOCKS) {
        const int e = blockIdx.x * 256 + threadIdx.x;
        if (e < NEDGES) {
            const int dn = __builtin_nontemporal_load(A + e);
            atomicAdd(&counts[dn], 1);
        }
        return;
    }
    const int lane = threadIdx.x & 15;
    const int f0   = lane << 2;
    const int g    = (blockIdx.x - CNT_BLOCKS) * 16 + (threadIdx.x >> 4);
    if (g >= NNODES + NREL) return;

    const float4 a00 = *(const float4*)(a_att +   0 + f0);
    const float4 a01 = *(const float4*)(a_att +  64 + f0);
    const float4 a10 = *(const float4*)(a_att + 128 + f0);
    const float4 a11 = *(const float4*)(a_att + 192 + f0);
    const float4 wv  = *(const float4*)(w + f0);

    float p0, p1;
    if (g < NNODES) {
        const float4 v = *(const float4*)(h + (size_t)g * FOUT + f0);
        p0 = v.x * a00.x + v.y * a00.y + v.z * a00.z + v.w * a00.w;
        p1 = v.x * wv.x * a10.x + v.y * wv.y * a10.y
           + v.z * wv.z * a10.z + v.w * wv.w * a10.w;
    } else {
        const float4 v = *(const float4*)(inputr + (size_t)(g - NNODES) * FOUT + f0);
        p0 = v.x * a01.x + v.y * a01.y + v.z * a01.z + v.w * a01.w;
        p1 = v.x * a11.x + v.y * a11.y + v.z * a11.z + v.w * a11.w;
    }
    #pragma unroll
    for (int off = 8; off >= 1; off >>= 1) {
        p0 += __shfl_xor(p0, off, 16);
        p1 += __shfl_xor(p1, off, 16);
    }
    if (lane == 0) {
        if (g < NNODES) hs2[g] = make_float2(p0, p1);
        else            rr2[g - NNODES] = make_float2(p0, p1);
    }
}

// Phase A: per-block exclusive scan of counts padded to multiple of 4.
__global__ __launch_bounds__(256) void scanA_kernel(
    const int* __restrict__ counts, int* __restrict__ sA, int* __restrict__ bsum)
{
    __shared__ int sm[256];
    const int t = threadIdx.x;
    const int i = blockIdx.x * 256 + t;
    const int c  = (i < NNODES) ? counts[i] : 0;
    const int ce = (c + 3) & ~3;                 // pad to multiple of 4
    sm[t] = ce;
    __syncthreads();
    for (int off = 1; off < 256; off <<= 1) {
        const int v = (t >= off) ? sm[t - off] : 0;
        __syncthreads();
        sm[t] += v;
        __syncthreads();
    }
    if (i < NNODES) sA[i] = sm[t] - ce;          // exclusive
    if (t == 255) bsum[blockIdx.x] = sm[255];
}

// Phase C (scanB folded in): every block scans the 196 block sums in LDS,
// picks its offset, writes start/next, and pre-writes pad sentinels.
__global__ __launch_bounds__(256) void scanC_kernel(
    const int* __restrict__ counts, const int* __restrict__ sA,
    const int* __restrict__ bsum,
    int* __restrict__ start, int* __restrict__ next, int* __restrict__ perm)
{
    __shared__ int sm[256];
    const int t = threadIdx.x;
    const int v0 = (t < NBLK) ? bsum[t] : 0;
    sm[t] = v0;
    __syncthreads();
    for (int off = 1; off < 256; off <<= 1) {
        const int v = (t >= off) ? sm[t - off] : 0;
        __syncthreads();
        sm[t] += v;
        __syncthreads();
    }
    const int boffset = (blockIdx.x == 0) ? 0 : sm[blockIdx.x - 1];
    const int i = blockIdx.x * 256 + t;
    if (i >= NNODES) return;
    const int s = sA[i] + boffset;
    start[i] = s;
    next[i]  = s;
    const int c = counts[i];
    const int padded = (c + 3) & ~3;
    for (int k = c; k < padded; k++) perm[s + k] = (int)PAD_SENTINEL;
    if (i == NNODES - 1) start[NNODES] = s + padded;
}

// Scatter packed (sn<<10 | rn) into CSR position by dst. A is streamed once
// (non-temporal) so it doesn't evict next/perm from L2.
__global__ __launch_bounds__(256) void scatter_kernel(
    const int* __restrict__ A, int* __restrict__ next, int* __restrict__ perm)
{
    const int e = blockIdx.x * blockDim.x + threadIdx.x;
    if (e >= NEDGES) return;
    const int dn = __builtin_nontemporal_load(A + e);
    const int rn = __builtin_nontemporal_load(A + NEDGES + e);
    const int sn = __builtin_nontemporal_load(A + 2 * NEDGES + e);
    const int pos = atomicAdd(&next[dn], 1);
    perm[pos] = (sn << 10) | rn;
}

// One wave per dst node; 4 x 16-lane quarters each own one edge of a group of
// 4; each lane owns a float4 of the 64 features. Pad sentinels contribute 0.
__global__ __launch_bounds__(256) void aggregate_kernel(
    const float* __restrict__ h, const float* __restrict__ inputr,
    const float* __restrict__ w,
    const int* __restrict__ perm, const int* __restrict__ start,
    const float2* __restrict__ hs2, const float2* __restrict__ rr2,
    float* __restrict__ out)
{
    const int wid  = (blockIdx.x * blockDim.x + threadIdx.x) >> 6;  // node id
    const int lane = threadIdx.x & 63;
    const int q    = lane >> 4;        // which edge of the group of 4
    const int f4   = (lane & 15) << 2; // feature base (float4)
    if (wid >= NNODES) return;

    const int b  = start[wid];
    const int e2 = start[wid + 1];     // padded end (e2-b multiple of 4)
    const float4 wl = *(const float4*)(w + f4);

    float4 acc0 = make_float4(0.f, 0.f, 0.f, 0.f);
    float4 acc1 = make_float4(0.f, 0.f, 0.f, 0.f);
    float sum0 = 0.f, sum1 = 0.f;

    for (int i = b + q; i < e2; i += 4) {
        const int p  = perm[i];                 // per-quarter broadcast
        const int sn = (p >> 10) & 0xFFFF;
        const int rn = p & 1023;

        const float2 hv = hs2[sn];
        const float2 rv = rr2[rn];
        const float sc0 = hv.x + rv.x;
        const float sc1 = hv.y + rv.y;
        float e0 = __expf(-fmaxf(sc0, NEG_SLOPE * sc0));
        float e1 = __expf(-fmaxf(sc1, NEG_SLOPE * sc1));
        if (p < 0) { e0 = 0.f; e1 = 0.f; }      // pad sentinel

        const float4 s = *(const float4*)(h      + (size_t)sn * FOUT + f4);
        const float4 r = *(const float4*)(inputr + (size_t)rn * FOUT + f4);

        acc0.x += (s.x - r.x) * e0;
        acc0.y += (s.y - r.y) * e0;
        acc0.z += (s.z - r.z) * e0;
        acc0.w += (s.w - r.w) * e0;
        acc1.x += fmaf(s.x, wl.x, -r.x) * e1;
        acc1.y += fmaf(s.y, wl.y, -r.y) * e1;
        acc1.z += fmaf(s.z, wl.z, -r.z) * e1;
        acc1.w += fmaf(s.w, wl.w, -r.w) * e1;
        sum0 += e0;
        sum1 += e1;
    }

    // Combine the 4 quarters: xor-16 then xor-32 swap-adds.
    #pragma unroll
    for (int off = 16; off <= 32; off <<= 1) {
        acc0.x += __shfl_xor(acc0.x, off);
        acc0.y += __shfl_xor(acc0.y, off);
        acc0.z += __shfl_xor(acc0.z, off);
        acc0.w += __shfl_xor(acc0.w, off);
        acc1.x += __shfl_xor(acc1.x, off);
        acc1.y += __shfl_xor(acc1.y, off);
        acc1.z += __shfl_xor(acc1.z, off);
        acc1.w += __shfl_xor(acc1.w, off);
        sum0   += __shfl_xor(sum0, off);
        sum1   += __shfl_xor(sum1, off);
    }

    if (q == 0) {
        const float inv = 1.0f / sum0;
        float4 o = make_float4(acc0.x * inv, acc0.y * inv, acc0.z * inv, acc0.w * inv);
        *(float4*)(out + (size_t)wid * FOUT + f4) = o;
    } else if (q == 1) {
        const float inv = 1.0f / sum1;
        float4 o = make_float4(acc1.x * inv, acc1.y * inv, acc1.z * inv, acc1.w * inv);
        *(float4*)(out + ((size_t)NNODES + wid) * FOUT + f4) = o;
    }
}

extern "C" void kernel_launch(void* const* d_in, const int* in_sizes, int n_in,
                              void* d_out, int out_size, void* d_ws, size_t ws_size,
                              hipStream_t stream) {
    const float* h      = (const float*)d_in[0];
    const float* inputr = (const float*)d_in[1];
    const int*   A      = (const int*)d_in[2];
    const float* w      = (const float*)d_in[3];
    const float* a_att  = (const float*)d_in[4];

    char* ws = (char*)d_ws;
    int*    counts = (int*)(ws + OFF_COUNTS);
    int*    start  = (int*)(ws + OFF_START);
    int*    next   = (int*)(ws + OFF_NEXT);
    int*    sA     = (int*)(ws + OFF_SA);
    int*    bsum   = (int*)(ws + OFF_BSUM);
    float2* hs2    = (float2*)(ws + OFF_HS);
    float2* rr2    = (float2*)(ws + OFF_RR);
    int*    perm   = (int*)(ws + OFF_PERM);
    float*  out    = (float*)d_out;

    hipMemsetAsync(counts, 0, sizeof(int) * NNODES, stream);

    // Fused histogram + score tables.
    prep_kernel<<<dim3(CNT_BLOCKS + PRE_BLOCKS), dim3(256), 0, stream>>>(
        h, inputr, w, a_att, A, counts, hs2, rr2);
    // Two-level exclusive scan (B folded into C) + sentinel padding.
    scanA_kernel<<<dim3(NBLK), dim3(256), 0, stream>>>(counts, sA, bsum);
    scanC_kernel<<<dim3(NBLK), dim3(256), 0, stream>>>(counts, sA, bsum, start, next, perm);
    // Scatter packed edge records into CSR order.
    scatter_kernel<<<dim3(CNT_BLOCKS), dim3(256), 0, stream>>>(A, next, perm);
    // Aggregate: one wave per dst node, 4 edges per iteration.
    aggregate_kernel<<<dim3((NNODES * 64) / 256), dim3(256), 0, stream>>>(
        h, inputr, w, perm, start, hs2, rr2, out);
}